// Round 8
// baseline (15.297 us; speedup 1.0000x reference)
//
#include <hip/hip_runtime.h>
#include <hip/hip_bf16.h>

// Problem constants (from reference):
//   B=32, S=512, D=768, N=128, LMAX=16
// Algebraic simplification (verified R1: absmax 0.031 << 0.385):
//   softmax over l sums to 1 per column m (row 0 always valid since len>=1),
//   then columns are masked by valid[m], so
//   agg[b,n,d] = sum_{m=0}^{len-1} embeddings[b, start+m, d].
//   W and b cancel entirely.
//
// R8: persistent 1-block/CU schedule. Insight from R6/R7 null results: the
// concurrent L2 read-window is ~(threads-per-CU/192)x32 spans ~ 2.7 batches
// ~ 4MB regardless of block partitioning -> always marginally thrashing the
// 4MB XCD L2 (plus 1.6MB write streams). Only 1 block/CU shrinks it:
// 256 blocks, each loops it=0..3; on iter it, ALL 32 blocks of XCD x work
// batch 4x+it -> window = exactly 1 batch (1.5MB) and batches walk
// sequentially. 12 waves/CU x ~11KB loads in flight = 132KB >> the ~22KB
// needed to cover HBM latency at this BW share.
// Plain stores only (R4 lesson: nt stores raced harness poison lines).

constexpr int B_    = 32;
constexpr int S_    = 512;
constexpr int D_    = 768;
constexpr int N_    = 128;
constexpr int LMAX_ = 16;
constexpr int TPS   = D_ / 4;       // 192 threads per span (f32x4 lanes)
constexpr int SPB   = 4;            // spans per block per iteration
constexpr int ITERS = 4;            // batches per XCD

typedef float f32x4 __attribute__((ext_vector_type(4)));

__global__ __launch_bounds__(SPB * TPS) void span_sum_kernel(
    const float* __restrict__ emb,     // [B,S,D]
    const int*   __restrict__ spans,   // [B,N,2] (start, inclusive end)
    float*       __restrict__ out)     // [B,N,D]
{
    const int bid = blockIdx.x;        // 0..255, 1 block per CU
    const int xcd = bid & 7;           // dispatch round-robins XCDs
    const int cu  = bid >> 3;          // 0..31 within XCD

    const int t    = threadIdx.x;      // 0..767
    const int sp   = t / TPS;          // 0..3 (192 = 3 full waves per span)
    const int lane = t - sp * TPS;     // 0..191

    const int n = (cu << 2) | sp;      // span index 0..127 (fixed per thread)

    #pragma unroll
    for (int it = 0; it < ITERS; ++it) {
        const int b   = (xcd << 2) + it;        // batch: all XCD-x blocks in step
        const int sid = b * N_ + n;

        const int start = spans[2 * sid + 0];
        const int lm1   = spans[2 * sid + 1] - start;   // len-1, in [0,15]

        const f32x4* __restrict__ row =
            reinterpret_cast<const f32x4*>(emb + (size_t)b * S_ * D_ + (size_t)start * D_) + lane;

        f32x4 acc = {0.f, 0.f, 0.f, 0.f};
        #pragma unroll
        for (int gq = 0; gq < LMAX_ / 4; ++gq) {
            if ((gq << 2) <= lm1) {                      // wave-uniform branch
                #pragma unroll
                for (int m4 = 0; m4 < 4; ++m4) {
                    const int  m  = (gq << 2) | m4;
                    const int  mm = (m <= lm1) ? m : lm1;     // clamp: dup = L1 hit
                    const float s = (m <= lm1) ? 1.0f : 0.0f; // mask
                    acc += s * row[(size_t)mm * (D_ / 4)];
                }
            }
        }

        *(reinterpret_cast<f32x4*>(out + (size_t)sid * D_) + lane) = acc;
    }
}

extern "C" void kernel_launch(void* const* d_in, const int* in_sizes, int n_in,
                              void* d_out, int out_size, void* d_ws, size_t ws_size,
                              hipStream_t stream) {
    const float* emb   = (const float*)d_in[0];   // [B,S,D] fp32
    // d_in[1] = W, d_in[2] = b : unused (cancel algebraically)
    const int*   spans = (const int*)d_in[3];     // [B,N,2] int32
    float*       out   = (float*)d_out;           // [B,N,D] fp32

    dim3 grid(256);               // 1 block per CU (persistent schedule)
    dim3 block(SPB * TPS);        // 768 threads = 12 waves
    span_sum_kernel<<<grid, block, 0, stream>>>(emb, spans, out);
}